// Round 10
// baseline (601.201 us; speedup 1.0000x reference)
//
#include <hip/hip_runtime.h>

#define BB 256
#define TT 1024
#define KK 64
#define CS 65

// One block per batch item, 512 threads = 8 waves.
//   wave0: forward chain  -- whole loop in ONE asm block, E matrix pinned in
//          physical v64-v127; readlanes software-pipelined across two 8-SGPR
//          banks (s36-43 / s44-51) so no VALU->SGPR->VALU RAW stalls.
//   wave1: Viterbi max-only chain -- same, ckpts ds_written every 16 steps
//   wave2: gold-path score (C++)
// Emission/mask loads are double-buffered: each 16-step body prefetches the
// NEXT iteration's data (masks into v144-159; emissions into the bank freed
// at body start), computes, then waits -- latency fully hidden.
// Phase B (all 8 waves): tie-exact argmax recompute per 32-step segment (C++,
// LDS Ccol), filling bpl. Then compose/backtrace epilogue (C++, proven).

__device__ __forceinline__ float rlane(float x, int i) {
  return __int_as_float(__builtin_amdgcn_readlane(__float_as_int(x), i));
}
#define RL(S, i) rlane(S, i)

__device__ __forceinline__ float wavemax(float v) {
#pragma unroll
  for (int off = 1; off <= 32; off <<= 1) v = fmaxf(v, __shfl_xor(v, off));
  return v;
}

// ======================= C++ helpers (head/tail/t1) =======================
#define CFQ4(S, a, b, c, d) \
  q0 = __builtin_fmaf(RL(S, a), Ecol[eb + (a)], q0); \
  q1 = __builtin_fmaf(RL(S, b), Ecol[eb + (b)], q1); \
  q2 = __builtin_fmaf(RL(S, c), Ecol[eb + (c)], q2); \
  q3 = __builtin_fmaf(RL(S, d), Ecol[eb + (d)], q3);
#define CFQALL(S) \
  CFQ4(S, 0, 1, 2, 3)     CFQ4(S, 4, 5, 6, 7)     CFQ4(S, 8, 9, 10, 11) \
  CFQ4(S, 12, 13, 14, 15) CFQ4(S, 16, 17, 18, 19) CFQ4(S, 20, 21, 22, 23) \
  CFQ4(S, 24, 25, 26, 27) CFQ4(S, 28, 29, 30, 31) CFQ4(S, 32, 33, 34, 35) \
  CFQ4(S, 36, 37, 38, 39) CFQ4(S, 40, 41, 42, 43) CFQ4(S, 44, 45, 46, 47) \
  CFQ4(S, 48, 49, 50, 51) CFQ4(S, 52, 53, 54, 55) CFQ4(S, 56, 57, 58, 59) \
  CFQ4(S, 60, 61, 62, 63)

#define CFWD_STEP(T_, E_, M_) { \
  int eb = jb65; asm volatile("" : "+v"(eb)); \
  float q0 = 0.f, q1 = 0.f, q2 = 0.f, q3 = 0.f; \
  CFQALL(x) \
  float q = (q0 + q1) + (q2 + q3); \
  q *= (E_); \
  q = (M_) ? q : x; \
  if (((T_) & 7) == 0) { \
    float gm = wavemax(x); \
    q *= __builtin_amdgcn_rcpf(gm); \
    offset += __logf(gm); \
  } \
  x = q; }

#define CVQ(g, a, b, c, d) float vm##g; { \
  float v0 = RL(x, a) + Ccol[cb + (a)]; \
  float v1 = RL(x, b) + Ccol[cb + (b)]; \
  float v2 = RL(x, c) + Ccol[cb + (c)]; \
  float v3 = RL(x, d) + Ccol[cb + (d)]; \
  vm##g = fmaxf(fmaxf(v0, v1), fmaxf(v2, v3)); }

#define CVIT_STEP(T_, E_, M_) { \
  int cb = jb65; asm volatile("" : "+v"(cb)); \
  CVQ(0, 0, 1, 2, 3)      CVQ(1, 4, 5, 6, 7)      CVQ(2, 8, 9, 10, 11) \
  CVQ(3, 12, 13, 14, 15)  CVQ(4, 16, 17, 18, 19)  CVQ(5, 20, 21, 22, 23) \
  CVQ(6, 24, 25, 26, 27)  CVQ(7, 28, 29, 30, 31)  CVQ(8, 32, 33, 34, 35) \
  CVQ(9, 36, 37, 38, 39)  CVQ(10, 40, 41, 42, 43) CVQ(11, 44, 45, 46, 47) \
  CVQ(12, 48, 49, 50, 51) CVQ(13, 52, 53, 54, 55) CVQ(14, 56, 57, 58, 59) \
  CVQ(15, 60, 61, 62, 63) \
  float b0 = fmaxf(vm0, vm1),   b1 = fmaxf(vm2, vm3); \
  float b2 = fmaxf(vm4, vm5),   b3 = fmaxf(vm6, vm7); \
  float b4 = fmaxf(vm8, vm9),   b5 = fmaxf(vm10, vm11); \
  float b6 = fmaxf(vm12, vm13), b7 = fmaxf(vm14, vm15); \
  float best = fmaxf(fmaxf(fmaxf(b0, b1), fmaxf(b2, b3)), \
                     fmaxf(fmaxf(b4, b5), fmaxf(b6, b7))); \
  float nd = (M_) ? (best + (E_)) : x; \
  x = nd; }

#define AG(i0, i1, i2, i3, i4, i5, i6, i7) { \
  float v0 = RL(x2, i0) + Ccol[db + (i0)]; \
  float v1 = RL(x2, i1) + Ccol[db + (i1)]; \
  float v2 = RL(x2, i2) + Ccol[db + (i2)]; \
  float v3 = RL(x2, i3) + Ccol[db + (i3)]; \
  float v4 = RL(x2, i4) + Ccol[db + (i4)]; \
  float v5 = RL(x2, i5) + Ccol[db + (i5)]; \
  float v6 = RL(x2, i6) + Ccol[db + (i6)]; \
  float v7 = RL(x2, i7) + Ccol[db + (i7)]; \
  bool p0 = v1 > v0; float a0 = p0 ? v1 : v0; int n0 = p0 ? (i1) : (i0); \
  bool p1 = v3 > v2; float a1 = p1 ? v3 : v2; int n1 = p1 ? (i3) : (i2); \
  bool p2 = v5 > v4; float a2 = p2 ? v5 : v4; int n2 = p2 ? (i5) : (i4); \
  bool p3 = v7 > v6; float a3 = p3 ? v7 : v6; int n3 = p3 ? (i7) : (i6); \
  bool r0 = a1 > a0; float bb0 = r0 ? a1 : a0; int m0 = r0 ? n1 : n0; \
  bool r1 = a3 > a2; float bb1 = r1 ? a3 : a2; int m1 = r1 ? n3 : n2; \
  bool s0 = bb1 > bb0; float gg = s0 ? bb1 : bb0; int w0 = s0 ? m1 : m0; \
  bool u0 = gg > bv; bv = u0 ? gg : bv; bi = u0 ? w0 : bi; }

// ============================ ASM text pieces ============================
// Two readlane banks: A = s36-43, B = s44-51. Consumers of bank A are
// emitted AFTER the readlanes of bank B (>=8 instr distance -> no stalls).
#define RLA(a,b,c,d,e,f,g,h) \
  "v_readlane_b32 s36, %[x], " #a "\n\t" \
  "v_readlane_b32 s37, %[x], " #b "\n\t" \
  "v_readlane_b32 s38, %[x], " #c "\n\t" \
  "v_readlane_b32 s39, %[x], " #d "\n\t" \
  "v_readlane_b32 s40, %[x], " #e "\n\t" \
  "v_readlane_b32 s41, %[x], " #f "\n\t" \
  "v_readlane_b32 s42, %[x], " #g "\n\t" \
  "v_readlane_b32 s43, %[x], " #h "\n\t"
#define RLB(a,b,c,d,e,f,g,h) \
  "v_readlane_b32 s44, %[x], " #a "\n\t" \
  "v_readlane_b32 s45, %[x], " #b "\n\t" \
  "v_readlane_b32 s46, %[x], " #c "\n\t" \
  "v_readlane_b32 s47, %[x], " #d "\n\t" \
  "v_readlane_b32 s48, %[x], " #e "\n\t" \
  "v_readlane_b32 s49, %[x], " #f "\n\t" \
  "v_readlane_b32 s50, %[x], " #g "\n\t" \
  "v_readlane_b32 s51, %[x], " #h "\n\t"

// Accumulator mapping identical to r9 (v20<-i%4==0, v21<-1, v22<-2, v23<-3).
#define FMA8F(E0,E1,E2,E3,E4,E5,E6,E7) \
  "v_mul_f32 v20, s36, v" #E0 "\n\t" \
  "v_mul_f32 v21, s37, v" #E1 "\n\t" \
  "v_mul_f32 v22, s38, v" #E2 "\n\t" \
  "v_mul_f32 v23, s39, v" #E3 "\n\t" \
  "v_fmac_f32 v20, s40, v" #E4 "\n\t" \
  "v_fmac_f32 v21, s41, v" #E5 "\n\t" \
  "v_fmac_f32 v22, s42, v" #E6 "\n\t" \
  "v_fmac_f32 v23, s43, v" #E7 "\n\t"
#define FMA8A(E0,E1,E2,E3,E4,E5,E6,E7) \
  "v_fmac_f32 v20, s36, v" #E0 "\n\t" \
  "v_fmac_f32 v21, s37, v" #E1 "\n\t" \
  "v_fmac_f32 v22, s38, v" #E2 "\n\t" \
  "v_fmac_f32 v23, s39, v" #E3 "\n\t" \
  "v_fmac_f32 v20, s40, v" #E4 "\n\t" \
  "v_fmac_f32 v21, s41, v" #E5 "\n\t" \
  "v_fmac_f32 v22, s42, v" #E6 "\n\t" \
  "v_fmac_f32 v23, s43, v" #E7 "\n\t"
#define FMA8B(E0,E1,E2,E3,E4,E5,E6,E7) \
  "v_fmac_f32 v20, s44, v" #E0 "\n\t" \
  "v_fmac_f32 v21, s45, v" #E1 "\n\t" \
  "v_fmac_f32 v22, s46, v" #E2 "\n\t" \
  "v_fmac_f32 v23, s47, v" #E3 "\n\t" \
  "v_fmac_f32 v20, s48, v" #E4 "\n\t" \
  "v_fmac_f32 v21, s49, v" #E5 "\n\t" \
  "v_fmac_f32 v22, s50, v" #E6 "\n\t" \
  "v_fmac_f32 v23, s51, v" #E7 "\n\t"

#define FWD_DOT_P \
  RLA(0,1,2,3,4,5,6,7) \
  RLB(8,9,10,11,12,13,14,15) \
  FMA8F(64,65,66,67,68,69,70,71) \
  RLA(16,17,18,19,20,21,22,23) \
  FMA8B(72,73,74,75,76,77,78,79) \
  RLB(24,25,26,27,28,29,30,31) \
  FMA8A(80,81,82,83,84,85,86,87) \
  RLA(32,33,34,35,36,37,38,39) \
  FMA8B(88,89,90,91,92,93,94,95) \
  RLB(40,41,42,43,44,45,46,47) \
  FMA8A(96,97,98,99,100,101,102,103) \
  RLA(48,49,50,51,52,53,54,55) \
  FMA8B(104,105,106,107,108,109,110,111) \
  RLB(56,57,58,59,60,61,62,63) \
  FMA8A(112,113,114,115,116,117,118,119) \
  FMA8B(120,121,122,123,124,125,126,127)

#define VG4(S0,S1,S2,S3,E0,E1,E2,E3,RED) \
  "v_add_f32 v16, " #S0 ", v" #E0 "\n\t" \
  "v_add_f32 v17, " #S1 ", v" #E1 "\n\t" \
  "v_add_f32 v18, " #S2 ", v" #E2 "\n\t" \
  "v_add_f32 v19, " #S3 ", v" #E3 "\n\t" \
  "v_max3_f32 v16, v16, v17, v18\n\t" \
  RED "\n\t"

#define VIT_DOT_P \
  RLA(0,1,2,3,4,5,6,7) \
  RLB(8,9,10,11,12,13,14,15) \
  VG4(s36,s37,s38,s39,64,65,66,67,"v_max_f32 v20, v16, v19") \
  VG4(s40,s41,s42,s43,68,69,70,71,"v_max3_f32 v20, v20, v16, v19") \
  RLA(16,17,18,19,20,21,22,23) \
  VG4(s44,s45,s46,s47,72,73,74,75,"v_max3_f32 v20, v20, v16, v19") \
  VG4(s48,s49,s50,s51,76,77,78,79,"v_max3_f32 v20, v20, v16, v19") \
  RLB(24,25,26,27,28,29,30,31) \
  VG4(s36,s37,s38,s39,80,81,82,83,"v_max3_f32 v20, v20, v16, v19") \
  VG4(s40,s41,s42,s43,84,85,86,87,"v_max3_f32 v20, v20, v16, v19") \
  RLA(32,33,34,35,36,37,38,39) \
  VG4(s44,s45,s46,s47,88,89,90,91,"v_max3_f32 v20, v20, v16, v19") \
  VG4(s48,s49,s50,s51,92,93,94,95,"v_max3_f32 v20, v20, v16, v19") \
  RLB(40,41,42,43,44,45,46,47) \
  VG4(s36,s37,s38,s39,96,97,98,99,"v_max3_f32 v20, v20, v16, v19") \
  VG4(s40,s41,s42,s43,100,101,102,103,"v_max3_f32 v20, v20, v16, v19") \
  RLA(48,49,50,51,52,53,54,55) \
  VG4(s44,s45,s46,s47,104,105,106,107,"v_max3_f32 v20, v20, v16, v19") \
  VG4(s48,s49,s50,s51,108,109,110,111,"v_max3_f32 v20, v20, v16, v19") \
  RLB(56,57,58,59,60,61,62,63) \
  VG4(s36,s37,s38,s39,112,113,114,115,"v_max3_f32 v20, v20, v16, v19") \
  VG4(s40,s41,s42,s43,116,117,118,119,"v_max3_f32 v20, v20, v16, v19") \
  VG4(s44,s45,s46,s47,120,121,122,123,"v_max3_f32 v20, v20, v16, v19") \
  VG4(s48,s49,s50,s51,124,125,126,127,"v_max3_f32 v20, v20, v16, v19")

#define AGLD(N,OFF) "global_load_dword v" #N ", v13, %[tp] offset:" #OFF "\n\t"
#define AGLE(N,OFF) "global_load_dword v" #N ", v12, %[ep] offset:" #OFF "\n\t"
#define AGLM(N,OFF) "global_load_dword v" #N ", v14, %[mp] offset:" #OFF "\n\t"

#define ELOADS \
  AGLD(64,0) AGLD(65,256) AGLD(66,512) AGLD(67,768) AGLD(68,1024) AGLD(69,1280) \
  AGLD(70,1536) AGLD(71,1792) AGLD(72,2048) AGLD(73,2304) AGLD(74,2560) AGLD(75,2816) \
  AGLD(76,3072) AGLD(77,3328) AGLD(78,3584) AGLD(79,3840) \
  "v_add_u32 v13, 0x1000, v13\n\t" \
  AGLD(80,0) AGLD(81,256) AGLD(82,512) AGLD(83,768) AGLD(84,1024) AGLD(85,1280) \
  AGLD(86,1536) AGLD(87,1792) AGLD(88,2048) AGLD(89,2304) AGLD(90,2560) AGLD(91,2816) \
  AGLD(92,3072) AGLD(93,3328) AGLD(94,3584) AGLD(95,3840) \
  "v_add_u32 v13, 0x1000, v13\n\t" \
  AGLD(96,0) AGLD(97,256) AGLD(98,512) AGLD(99,768) AGLD(100,1024) AGLD(101,1280) \
  AGLD(102,1536) AGLD(103,1792) AGLD(104,2048) AGLD(105,2304) AGLD(106,2560) AGLD(107,2816) \
  AGLD(108,3072) AGLD(109,3328) AGLD(110,3584) AGLD(111,3840) \
  "v_add_u32 v13, 0x1000, v13\n\t" \
  AGLD(112,0) AGLD(113,256) AGLD(114,512) AGLD(115,768) AGLD(116,1024) AGLD(117,1280) \
  AGLD(118,1536) AGLD(119,1792) AGLD(120,2048) AGLD(121,2304) AGLD(122,2560) AGLD(123,2816) \
  AGLD(124,3072) AGLD(125,3328) AGLD(126,3584) AGLD(127,3840)

#define AMUL(N) "v_mul_f32 v" #N ", 0x3fb8aa3b, v" #N "\n\t"
#define AEXI(N) "v_exp_f32 v" #N ", v" #N "\n\t"
#define EEXPALL \
  AMUL(64) AMUL(65) AMUL(66) AMUL(67) AMUL(68) AMUL(69) AMUL(70) AMUL(71) \
  AMUL(72) AMUL(73) AMUL(74) AMUL(75) AMUL(76) AMUL(77) AMUL(78) AMUL(79) \
  AMUL(80) AMUL(81) AMUL(82) AMUL(83) AMUL(84) AMUL(85) AMUL(86) AMUL(87) \
  AMUL(88) AMUL(89) AMUL(90) AMUL(91) AMUL(92) AMUL(93) AMUL(94) AMUL(95) \
  AMUL(96) AMUL(97) AMUL(98) AMUL(99) AMUL(100) AMUL(101) AMUL(102) AMUL(103) \
  AMUL(104) AMUL(105) AMUL(106) AMUL(107) AMUL(108) AMUL(109) AMUL(110) AMUL(111) \
  AMUL(112) AMUL(113) AMUL(114) AMUL(115) AMUL(116) AMUL(117) AMUL(118) AMUL(119) \
  AMUL(120) AMUL(121) AMUL(122) AMUL(123) AMUL(124) AMUL(125) AMUL(126) AMUL(127) \
  AEXI(64) AEXI(65) AEXI(66) AEXI(67) AEXI(68) AEXI(69) AEXI(70) AEXI(71) \
  AEXI(72) AEXI(73) AEXI(74) AEXI(75) AEXI(76) AEXI(77) AEXI(78) AEXI(79) \
  AEXI(80) AEXI(81) AEXI(82) AEXI(83) AEXI(84) AEXI(85) AEXI(86) AEXI(87) \
  AEXI(88) AEXI(89) AEXI(90) AEXI(91) AEXI(92) AEXI(93) AEXI(94) AEXI(95) \
  AEXI(96) AEXI(97) AEXI(98) AEXI(99) AEXI(100) AEXI(101) AEXI(102) AEXI(103) \
  AEXI(104) AEXI(105) AEXI(106) AEXI(107) AEXI(108) AEXI(109) AEXI(110) AEXI(111) \
  AEXI(112) AEXI(113) AEXI(114) AEXI(115) AEXI(116) AEXI(117) AEXI(118) AEXI(119) \
  AEXI(120) AEXI(121) AEXI(122) AEXI(123) AEXI(124) AEXI(125) AEXI(126) AEXI(127)

#define EMIS16 \
  AGLE(40,0) AGLE(41,256) AGLE(42,512) AGLE(43,768) AGLE(44,1024) AGLE(45,1280) \
  AGLE(46,1536) AGLE(47,1792) AGLE(48,2048) AGLE(49,2304) AGLE(50,2560) AGLE(51,2816) \
  AGLE(52,3072) AGLE(53,3328) AGLE(54,3584) AGLE(55,3840)
#define EMIS8 \
  AGLE(40,0) AGLE(41,256) AGLE(42,512) AGLE(43,768) AGLE(44,1024) AGLE(45,1280) \
  AGLE(46,1536) AGLE(47,1792)
#define EMIS16B \
  AGLE(24,0) AGLE(25,256) AGLE(26,512) AGLE(27,768) AGLE(28,1024) AGLE(29,1280) \
  AGLE(30,1536) AGLE(31,1792) AGLE(32,2048) AGLE(33,2304) AGLE(34,2560) AGLE(35,2816) \
  AGLE(36,3072) AGLE(37,3328) AGLE(38,3584) AGLE(39,3840)
#define EMIS8B \
  AGLE(24,0) AGLE(25,256) AGLE(26,512) AGLE(27,768) AGLE(28,1024) AGLE(29,1280) \
  AGLE(30,1536) AGLE(31,1792)
#define MASK16 \
  AGLM(128,0) AGLM(129,4) AGLM(130,8) AGLM(131,12) AGLM(132,16) AGLM(133,20) \
  AGLM(134,24) AGLM(135,28) AGLM(136,32) AGLM(137,36) AGLM(138,40) AGLM(139,44) \
  AGLM(140,48) AGLM(141,52) AGLM(142,56) AGLM(143,60)
#define MASK16B \
  AGLM(144,0) AGLM(145,4) AGLM(146,8) AGLM(147,12) AGLM(148,16) AGLM(149,20) \
  AGLM(150,24) AGLM(151,28) AGLM(152,32) AGLM(153,36) AGLM(154,40) AGLM(155,44) \
  AGLM(156,48) AGLM(157,52) AGLM(158,56) AGLM(159,60)
#define MASK8B \
  AGLM(144,0) AGLM(145,4) AGLM(146,8) AGLM(147,12) AGLM(148,16) AGLM(149,20) \
  AGLM(150,24) AGLM(151,28)

#define MOVMSK \
  "v_mov_b32 v128, v144\n\tv_mov_b32 v129, v145\n\tv_mov_b32 v130, v146\n\t" \
  "v_mov_b32 v131, v147\n\tv_mov_b32 v132, v148\n\tv_mov_b32 v133, v149\n\t" \
  "v_mov_b32 v134, v150\n\tv_mov_b32 v135, v151\n\tv_mov_b32 v136, v152\n\t" \
  "v_mov_b32 v137, v153\n\tv_mov_b32 v138, v154\n\tv_mov_b32 v139, v155\n\t" \
  "v_mov_b32 v140, v156\n\tv_mov_b32 v141, v157\n\tv_mov_b32 v142, v158\n\t" \
  "v_mov_b32 v143, v159\n\t"
#define MOVEMI \
  "v_mov_b32 v40, v24\n\tv_mov_b32 v41, v25\n\tv_mov_b32 v42, v26\n\t" \
  "v_mov_b32 v43, v27\n\tv_mov_b32 v44, v28\n\tv_mov_b32 v45, v29\n\t" \
  "v_mov_b32 v46, v30\n\tv_mov_b32 v47, v31\n\tv_mov_b32 v48, v32\n\t" \
  "v_mov_b32 v49, v33\n\tv_mov_b32 v50, v34\n\tv_mov_b32 v51, v35\n\t" \
  "v_mov_b32 v52, v36\n\tv_mov_b32 v53, v37\n\tv_mov_b32 v54, v38\n\t" \
  "v_mov_b32 v55, v39\n\t"

#define AEM(D,R) "v_mul_f32 v" #D ", 0x3fb8aa3b, v" #R "\n\t"
#define EMEXP16 \
  AEM(24,40) AEM(25,41) AEM(26,42) AEM(27,43) AEM(28,44) AEM(29,45) AEM(30,46) AEM(31,47) \
  AEM(32,48) AEM(33,49) AEM(34,50) AEM(35,51) AEM(36,52) AEM(37,53) AEM(38,54) AEM(39,55) \
  AEXI(24) AEXI(25) AEXI(26) AEXI(27) AEXI(28) AEXI(29) AEXI(30) AEXI(31) \
  AEXI(32) AEXI(33) AEXI(34) AEXI(35) AEXI(36) AEXI(37) AEXI(38) AEXI(39)
#define EMEXP8 \
  AEM(24,40) AEM(25,41) AEM(26,42) AEM(27,43) AEM(28,44) AEM(29,45) AEM(30,46) AEM(31,47) \
  AEXI(24) AEXI(25) AEXI(26) AEXI(27) AEXI(28) AEXI(29) AEXI(30) AEXI(31)

#define AFSTEP_P(MR,EV) \
  "v_cmp_ne_u32 vcc, 0, v" #MR "\n\t" \
  FWD_DOT_P \
  "v_add_f32 v16, v20, v21\n\t" \
  "v_add_f32 v17, v22, v23\n\t" \
  "v_add_f32 v16, v16, v17\n\t" \
  "v_mul_f32 v16, v16, v" #EV "\n\t" \
  "v_cndmask_b32 %[x], %[x], v16, vcc\n\t"

#define RNRM \
  "v_mov_b32 v17, %[x]\n\t" \
  "ds_swizzle_b32 v18, v17 offset:0x041F\n\t" \
  "s_waitcnt lgkmcnt(0)\n\t" \
  "v_max_f32 v17, v17, v18\n\t" \
  "ds_swizzle_b32 v18, v17 offset:0x081F\n\t" \
  "s_waitcnt lgkmcnt(0)\n\t" \
  "v_max_f32 v17, v17, v18\n\t" \
  "ds_swizzle_b32 v18, v17 offset:0x101F\n\t" \
  "s_waitcnt lgkmcnt(0)\n\t" \
  "v_max_f32 v17, v17, v18\n\t" \
  "ds_swizzle_b32 v18, v17 offset:0x201F\n\t" \
  "s_waitcnt lgkmcnt(0)\n\t" \
  "v_max_f32 v17, v17, v18\n\t" \
  "ds_swizzle_b32 v18, v17 offset:0x401F\n\t" \
  "s_waitcnt lgkmcnt(0)\n\t" \
  "v_max_f32 v17, v17, v18\n\t" \
  "v_readlane_b32 s56, v17, 0\n\t" \
  "v_readlane_b32 s57, v17, 32\n\t" \
  "v_mov_b32 v18, s57\n\t" \
  "v_max_f32 v18, s56, v18\n\t" \
  "v_readlane_b32 s56, v18, 0\n\t"

#define AFSTEPR_P(MR,EV) \
  "v_cmp_ne_u32 vcc, 0, v" #MR "\n\t" \
  FWD_DOT_P \
  "v_add_f32 v16, v20, v21\n\t" \
  "v_add_f32 v17, v22, v23\n\t" \
  "v_add_f32 v16, v16, v17\n\t" \
  "v_mul_f32 v16, v16, v" #EV "\n\t" \
  RNRM \
  "v_cndmask_b32 %[x], %[x], v16, vcc\n\t" \
  "v_rcp_f32 v18, s56\n\t" \
  "v_log_f32 v19, s56\n\t" \
  "v_mul_f32 %[x], %[x], v18\n\t" \
  "v_fmac_f32 %[off], 0x3f317218, v19\n\t"

#define AVSTEP_P(MR,EV) \
  "v_cmp_ne_u32 vcc, 0, v" #MR "\n\t" \
  VIT_DOT_P \
  "v_add_f32 v16, v20, v" #EV "\n\t" \
  "v_cndmask_b32 %[x], %[x], v16, vcc\n\t"

// ---- 16-step bodies (single body; B->A reg moves keep I$ footprint small) --
#define FSTEPS16 \
  AFSTEPR_P(128,24) AFSTEP_P(129,25) AFSTEP_P(130,26) AFSTEP_P(131,27) \
  AFSTEP_P(132,28)  AFSTEP_P(133,29) AFSTEP_P(134,30) AFSTEP_P(135,31) \
  AFSTEPR_P(136,32) AFSTEP_P(137,33) AFSTEP_P(138,34) AFSTEP_P(139,35) \
  AFSTEP_P(140,36)  AFSTEP_P(141,37) AFSTEP_P(142,38) AFSTEP_P(143,39)
#define VSTEPS16 \
  AVSTEP_P(128,40) AVSTEP_P(129,41) AVSTEP_P(130,42) AVSTEP_P(131,43) \
  AVSTEP_P(132,44) AVSTEP_P(133,45) AVSTEP_P(134,46) AVSTEP_P(135,47) \
  AVSTEP_P(136,48) AVSTEP_P(137,49) AVSTEP_P(138,50) AVSTEP_P(139,51) \
  AVSTEP_P(140,52) AVSTEP_P(141,53) AVSTEP_P(142,54) AVSTEP_P(143,55)

#define CLOBS \
  "v11","v12","v13","v14","v16","v17","v18","v19","v20","v21","v22","v23", \
  "v24","v25","v26","v27","v28","v29","v30","v31","v32","v33","v34","v35", \
  "v36","v37","v38","v39","v40","v41","v42","v43","v44","v45","v46","v47", \
  "v48","v49","v50","v51","v52","v53","v54","v55", \
  "v64","v65","v66","v67","v68","v69","v70","v71","v72","v73","v74","v75", \
  "v76","v77","v78","v79","v80","v81","v82","v83","v84","v85","v86","v87", \
  "v88","v89","v90","v91","v92","v93","v94","v95","v96","v97","v98","v99", \
  "v100","v101","v102","v103","v104","v105","v106","v107","v108","v109", \
  "v110","v111","v112","v113","v114","v115","v116","v117","v118","v119", \
  "v120","v121","v122","v123","v124","v125","v126","v127","v128","v129", \
  "v130","v131","v132","v133","v134","v135","v136","v137","v138","v139", \
  "v140","v141","v142","v143","v144","v145","v146","v147","v148","v149", \
  "v150","v151","v152","v153","v154","v155","v156","v157","v158","v159", \
  "s36","s37","s38","s39","s40","s41","s42","s43","s44","s45","s46","s47", \
  "s48","s49","s50","s51","s55","s56","s57","s58","s59","vcc","scc","memory"

__global__ __launch_bounds__(512)
__attribute__((amdgpu_waves_per_eu(1, 2)))
void crf_mega_kernel(
    const float* __restrict__ em, const int* __restrict__ mask,
    const float* __restrict__ trans, const int* __restrict__ tags,
    float* __restrict__ out_dec, float* ll_sum, int* match, int* maskSum) {

  __shared__ float Ecol[KK * CS];               // exp(T) columns (C++ head/t1)
  __shared__ float Ccol[KK * CS];               // raw T columns (tail + phase B)
  __shared__ __align__(16) float ckw[64][KK];   // vit deltas every 16 steps
  __shared__ float fin[KK];                     // final vit delta (t=1023)
  __shared__ unsigned char mrow[TT];
  __shared__ unsigned char bpl[TT][KK];
  __shared__ unsigned char segm[32][KK];
  __shared__ unsigned char bs[40];
  __shared__ int redm[32];

  const int b = blockIdx.x;
  const int tid = threadIdx.x;
  const int wv = tid >> 6;
  const int j = tid & 63;
  const int jb65 = j * CS;

  const float* emb = em + (size_t)b * TT * KK;
  const int* mb = mask + (size_t)b * TT;
  const int* tgb = tags + (size_t)b * TT;

  for (int t = tid; t < TT; t += 512) mrow[t] = (unsigned char)(mb[t] ? 1 : 0);
  if (wv == 0) {
#pragma unroll 4
    for (int i = 0; i < KK; ++i) Ecol[jb65 + i] = __expf(trans[i * KK + j]);
  } else if (wv == 1) {
#pragma unroll 4
    for (int i = 0; i < KK; ++i) Ccol[jb65 + i] = trans[i * KK + j];
  }
  __syncthreads();  // B0

  if (wv == 0) {
    // =========================== FORWARD (wave 0) ===========================
    float raw = emb[j];
    float x, offset;
    {  // t = 1 special
      float m0 = wavemax(raw);
      offset = m0;
      float s = __expf(raw - m0);
      int eb = jb65; asm volatile("" : "+v"(eb));
      float q0 = 0.f, q1 = 0.f, q2 = 0.f, q3 = 0.f;
      CFQALL(s)
      float q = (q0 + q1) + (q2 + q3);
      q *= __expf(emb[KK + j]);
      x = mrow[1] ? q : s;
    }
    // head t = 2..7 (no renorm in range)
    for (int t = 2; t <= 7; ++t) {
      float e = __expf(emb[(size_t)t * KK + j]);
      int m = mrow[t];
      CFWD_STEP(t, e, m)
    }
    // asm chain t = 8..1023: 62-iter loop + peeled iter62 + 8-step tail.
    asm volatile(
      "s_mov_b32 s55, 0\n\t"
      "v_mov_b32 v12, %[vo]\n\t"
      "v_mov_b32 v13, %[jo]\n\t"
      "v_mov_b32 v14, 32\n\t"
      ELOADS
      MASK16
      EMIS16
      "s_waitcnt vmcnt(0)\n\t"
      EEXPALL
      "9:\n\t"
      EMEXP16
      "v_add_u32 v12, 0x1000, v12\n\t"
      EMIS16
      "v_add_u32 v14, 64, v14\n\t"
      MASK16B
      FSTEPS16
      "s_waitcnt vmcnt(0)\n\t"
      MOVMSK
      "s_add_u32 s55, s55, 1\n\t"
      "s_cmp_lt_u32 s55, 62\n\t"
      "s_cbranch_scc1 9b\n\t"
      // peeled iter 62 (t=1000..1015): prefetch 8-step tail into B regs
      EMEXP16
      "v_add_u32 v12, 0x1000, v12\n\t"
      EMIS8
      "v_add_u32 v14, 64, v14\n\t"
      MASK8B
      FSTEPS16
      "s_waitcnt vmcnt(0)\n\t"
      // tail t = 1016..1023 (renorm at 1016 only)
      EMEXP8
      AFSTEPR_P(144,24) AFSTEP_P(145,25) AFSTEP_P(146,26) AFSTEP_P(147,27)
      AFSTEP_P(148,28)  AFSTEP_P(149,29) AFSTEP_P(150,30) AFSTEP_P(151,31)
      "s_waitcnt vmcnt(0) lgkmcnt(0)\n\t"
      : [x]"+v"(x), [off]"+v"(offset)
      : [ep]"s"(emb), [mp]"s"(mb), [tp]"s"(trans),
        [vo]"v"(2048 + 4 * j), [jo]"v"(4 * j)
      : CLOBS);

    float ssum = x;
#pragma unroll
    for (int off = 1; off <= 32; off <<= 1) ssum += __shfl_xor(ssum, off);
    if (tid == 0) atomicAdd(ll_sum, -(offset + __logf(ssum)));

  } else if (wv == 1) {
    // ====================== VITERBI max-only (wave 1) ======================
    float x = emb[j];
    unsigned ckoff = (unsigned)(unsigned long long)(&ckw[1][j]);
    asm volatile(
      "s_mov_b32 s55, 0\n\t"
      "v_mov_b32 v11, %[ck]\n\t"
      "v_mov_b32 v12, %[vo]\n\t"
      "v_mov_b32 v13, %[jo]\n\t"
      "v_mov_b32 v14, 4\n\t"
      ELOADS
      MASK16
      EMIS16
      "s_waitcnt vmcnt(0)\n\t"
      "8:\n\t"
      "v_add_u32 v12, 0x1000, v12\n\t"
      EMIS16B
      "v_add_u32 v14, 64, v14\n\t"
      MASK16B
      VSTEPS16
      "ds_write_b32 v11, %[x]\n\t"
      "v_add_u32 v11, 0x100, v11\n\t"
      "s_waitcnt vmcnt(0)\n\t"
      MOVEMI
      MOVMSK
      "s_add_u32 s55, s55, 1\n\t"
      "s_cmp_lt_u32 s55, 62\n\t"
      "s_cbranch_scc1 8b\n\t"
      // peeled iter 62 (t=993..1008): prefetch 8-step tail into B regs
      "v_add_u32 v12, 0x1000, v12\n\t"
      EMIS8B
      "v_add_u32 v14, 64, v14\n\t"
      MASK8B
      VSTEPS16
      "ds_write_b32 v11, %[x]\n\t"
      "s_waitcnt vmcnt(0)\n\t"
      // tail t = 1009..1016
      AVSTEP_P(144,24) AVSTEP_P(145,25) AVSTEP_P(146,26) AVSTEP_P(147,27)
      AVSTEP_P(148,28) AVSTEP_P(149,29) AVSTEP_P(150,30) AVSTEP_P(151,31)
      "s_waitcnt vmcnt(0) lgkmcnt(0)\n\t"
      : [x]"+v"(x)
      : [ep]"s"(emb), [mp]"s"(mb), [tp]"s"(trans),
        [vo]"v"(256 + 4 * j), [jo]"v"(4 * j), [ck]"v"(ckoff)
      : CLOBS);
    // C++ tail t = 1017..1023 (7 steps)
    for (int t = TT - 7; t <= TT - 1; ++t) {
      float e = emb[(size_t)t * KK + j];
      int m = mrow[t];
      CVIT_STEP(t, e, m)
    }
    fin[j] = x;

  } else if (wv == 2) {
    // ========================= PATH SCORE (wave 2) =========================
    float acc = 0.f;
    int cnt = 0;
    for (int t = j; t < TT; t += 64) {
      if (mb[t]) {
        int tg = tgb[t];
        acc += emb[(size_t)t * KK + tg];
        cnt += 1;
        if (t >= 1) acc += trans[tgb[t - 1] * KK + tg];
      }
    }
#pragma unroll
    for (int off = 1; off <= 32; off <<= 1) {
      acc += __shfl_xor(acc, off);
      cnt += __shfl_xor(cnt, off);
    }
    if (j == 0) { atomicAdd(ll_sum, acc); atomicAdd(maskSum, cnt); }
  }
  // waves 3-7 fall through.

  __syncthreads();  // B1 — phase boundary (orders ckw, fin, Ccol)

  // ====== PHASE B: per-segment argmax recompute (8 waves x 4 segments) ======
#pragma unroll 1
  for (int kk = 0; kk < 4; ++kk) {
    int s = wv + 8 * kk;
    int tS = 32 * s + 1;
    int tE = (s == 31) ? (TT - 1) : (32 * s + 32);
    float x2 = (s == 0) ? emb[j] : ckw[2 * s][j];
    float e_nx = emb[(size_t)tS * KK + j];
#pragma unroll 1
    for (int t = tS; t <= tE; ++t) {
      float e = e_nx;
      if (t < tE) e_nx = emb[(size_t)(t + 1) * KK + j];
      int db = jb65; asm volatile("" : "+v"(db));
      float bv = -__builtin_inff(); int bi = 0;
      AG(0, 1, 2, 3, 4, 5, 6, 7)        AG(8, 9, 10, 11, 12, 13, 14, 15)
      AG(16, 17, 18, 19, 20, 21, 22, 23) AG(24, 25, 26, 27, 28, 29, 30, 31)
      AG(32, 33, 34, 35, 36, 37, 38, 39) AG(40, 41, 42, 43, 44, 45, 46, 47)
      AG(48, 49, 50, 51, 52, 53, 54, 55) AG(56, 57, 58, 59, 60, 61, 62, 63)
      int m = mrow[t];
      float nd = m ? (bv + e) : x2;
      int bp = m ? bi : j;
      bpl[t][j] = (unsigned char)bp;
      x2 = nd;
    }
  }
  __syncthreads();  // B2

  // ---- compose 32-step segment maps (4 chains per thread, ILP) ----
  {
    int j0 = tid & 63;
    int sg = tid >> 6;
    int xs[4]; int tS[4], tE[4];
#pragma unroll
    for (int kk = 0; kk < 4; ++kk) {
      int s = sg + 8 * kk;
      xs[kk] = j0;
      tS[kk] = 32 * s + 1;
      tE[kk] = (s == 31) ? (TT - 1) : (32 * s + 32);
    }
    for (int q = 0; q < 32; ++q) {
#pragma unroll
      for (int kk = 0; kk < 4; ++kk) {
        int t = tE[kk] - q;
        if (t >= tS[kk]) xs[kk] = bpl[t][xs[kk]];
      }
    }
#pragma unroll
    for (int kk = 0; kk < 4; ++kk) segm[sg + 8 * kk][j0] = (unsigned char)xs[kk];
  }
  __syncthreads();  // B3

  if (tid == 0) {   // last-tag argmax (strict >, first max) + boundary walk
    float bd = fin[0];
    int lt = 0;
    for (int i = 1; i < KK; ++i) {
      float v2 = fin[i];
      if (v2 > bd) { bd = v2; lt = i; }
    }
    bs[32] = (unsigned char)lt;
    for (int s = 31; s >= 0; --s) bs[s] = segm[s][bs[s + 1]];
  }
  __syncthreads();  // B4

  if (tid < 32) {   // per-segment backtrace
    int s = tid;
    int x = bs[s + 1];
    int cnt = 0;
    int tEnd = (s == 31) ? (TT - 1) : (32 * s + 32);
    if (s == 31) {
      int m = mrow[TT - 1];
      out_dec[(size_t)b * TT + TT - 1] = (float)(m ? x : 0);
      cnt += (m && x == tgb[TT - 1]);
    }
    for (int t = tEnd; t >= 32 * s + 1; --t) {
      x = bpl[t][x];
      int m2 = mrow[t - 1];
      out_dec[(size_t)b * TT + t - 1] = (float)(m2 ? x : 0);
      cnt += (m2 && x == tgb[t - 1]);
    }
    redm[s] = cnt;
  }
  __syncthreads();  // B5
  if (tid == 0) {
    int c = 0;
    for (int s = 0; s < 32; ++s) c += redm[s];
    atomicAdd(match, c);
  }
}

__global__ void finalize_kernel(const float* ll_sum, const int* match,
                                const int* maskSum, float* d_out) {
  d_out[0] = -(*ll_sum) / (float)BB;
  d_out[1 + BB * TT] = (float)(*match) / (float)(*maskSum);
}

extern "C" void kernel_launch(void* const* d_in, const int* in_sizes, int n_in,
                              void* d_out, int out_size, void* d_ws, size_t ws_size,
                              hipStream_t stream) {
  const float* em = (const float*)d_in[0];
  const int* tags = (const int*)d_in[1];
  const int* mask = (const int*)d_in[2];       // bool -> int32 on device
  const float* trans = (const float*)d_in[3];
  float* out = (float*)d_out;

  float* ll_sum = (float*)d_ws;
  int* match = (int*)((char*)d_ws + 4);
  int* maskSum = (int*)((char*)d_ws + 8);

  hipMemsetAsync(d_ws, 0, 12, stream);
  crf_mega_kernel<<<BB, 512, 0, stream>>>(em, mask, trans, tags, out + 1,
                                          ll_sum, match, maskSum);
  finalize_kernel<<<1, 1, 0, stream>>>(ll_sum, match, maskSum, out);
}

// Round 11
// 498.463 us; speedup vs baseline: 1.2061x; 1.2061x over previous
//
#include <hip/hip_runtime.h>

#define BB 256
#define TT 1024
#define KK 64
#define CS 65

// One block per batch item, 512 threads = 8 waves.
//   wave0: forward chain  -- one asm block; E (exp'd) pinned in v64-v127;
//          x broadcast via LDS (ds_write lane slot + 16 uniform ds_read_b128
//          -> v160-v223 pairs), dot via 32 v_pk_fma_f32.  ~63 instr/step.
//   wave1: Viterbi max-only chain -- C pinned in v64-v127; 32 v_pk_add_f32
//          in place + 32-op v_max3 tree.  ~90 instr/step.
//   wave2: gold-path score (C++)
// Counted lgkmcnt(12/8/4/0) waits overlap the LDS broadcast latency with the
// packed math. r10 lesson: scheduling rearrangements are null -- only
// instruction COUNT moves a lone-wave serial chain.
// Phase B (all 8 waves): tie-exact argmax recompute per 32-step segment (C++,
// LDS Ccol), filling bpl. Then compose/backtrace epilogue (C++, proven).

__device__ __forceinline__ float rlane(float x, int i) {
  return __int_as_float(__builtin_amdgcn_readlane(__float_as_int(x), i));
}
#define RL(S, i) rlane(S, i)

__device__ __forceinline__ float wavemax(float v) {
#pragma unroll
  for (int off = 1; off <= 32; off <<= 1) v = fmaxf(v, __shfl_xor(v, off));
  return v;
}

// ======================= C++ helpers (head/tail/t1) =======================
#define CFQ4(S, a, b, c, d) \
  q0 = __builtin_fmaf(RL(S, a), Ecol[eb + (a)], q0); \
  q1 = __builtin_fmaf(RL(S, b), Ecol[eb + (b)], q1); \
  q2 = __builtin_fmaf(RL(S, c), Ecol[eb + (c)], q2); \
  q3 = __builtin_fmaf(RL(S, d), Ecol[eb + (d)], q3);
#define CFQALL(S) \
  CFQ4(S, 0, 1, 2, 3)     CFQ4(S, 4, 5, 6, 7)     CFQ4(S, 8, 9, 10, 11) \
  CFQ4(S, 12, 13, 14, 15) CFQ4(S, 16, 17, 18, 19) CFQ4(S, 20, 21, 22, 23) \
  CFQ4(S, 24, 25, 26, 27) CFQ4(S, 28, 29, 30, 31) CFQ4(S, 32, 33, 34, 35) \
  CFQ4(S, 36, 37, 38, 39) CFQ4(S, 40, 41, 42, 43) CFQ4(S, 44, 45, 46, 47) \
  CFQ4(S, 48, 49, 50, 51) CFQ4(S, 52, 53, 54, 55) CFQ4(S, 56, 57, 58, 59) \
  CFQ4(S, 60, 61, 62, 63)

#define CFWD_STEP(T_, E_, M_) { \
  int eb = jb65; asm volatile("" : "+v"(eb)); \
  float q0 = 0.f, q1 = 0.f, q2 = 0.f, q3 = 0.f; \
  CFQALL(x) \
  float q = (q0 + q1) + (q2 + q3); \
  q *= (E_); \
  q = (M_) ? q : x; \
  if (((T_) & 7) == 0) { \
    float gm = wavemax(x); \
    q *= __builtin_amdgcn_rcpf(gm); \
    offset += __logf(gm); \
  } \
  x = q; }

#define CVQ(g, a, b, c, d) float vm##g; { \
  float v0 = RL(x, a) + Ccol[cb + (a)]; \
  float v1 = RL(x, b) + Ccol[cb + (b)]; \
  float v2 = RL(x, c) + Ccol[cb + (c)]; \
  float v3 = RL(x, d) + Ccol[cb + (d)]; \
  vm##g = fmaxf(fmaxf(v0, v1), fmaxf(v2, v3)); }

#define CVIT_STEP(T_, E_, M_) { \
  int cb = jb65; asm volatile("" : "+v"(cb)); \
  CVQ(0, 0, 1, 2, 3)      CVQ(1, 4, 5, 6, 7)      CVQ(2, 8, 9, 10, 11) \
  CVQ(3, 12, 13, 14, 15)  CVQ(4, 16, 17, 18, 19)  CVQ(5, 20, 21, 22, 23) \
  CVQ(6, 24, 25, 26, 27)  CVQ(7, 28, 29, 30, 31)  CVQ(8, 32, 33, 34, 35) \
  CVQ(9, 36, 37, 38, 39)  CVQ(10, 40, 41, 42, 43) CVQ(11, 44, 45, 46, 47) \
  CVQ(12, 48, 49, 50, 51) CVQ(13, 52, 53, 54, 55) CVQ(14, 56, 57, 58, 59) \
  CVQ(15, 60, 61, 62, 63) \
  float b0 = fmaxf(vm0, vm1),   b1 = fmaxf(vm2, vm3); \
  float b2 = fmaxf(vm4, vm5),   b3 = fmaxf(vm6, vm7); \
  float b4 = fmaxf(vm8, vm9),   b5 = fmaxf(vm10, vm11); \
  float b6 = fmaxf(vm12, vm13), b7 = fmaxf(vm14, vm15); \
  float best = fmaxf(fmaxf(fmaxf(b0, b1), fmaxf(b2, b3)), \
                     fmaxf(fmaxf(b4, b5), fmaxf(b6, b7))); \
  float nd = (M_) ? (best + (E_)) : x; \
  x = nd; }

#define AG(i0, i1, i2, i3, i4, i5, i6, i7) { \
  float v0 = RL(x2, i0) + Ccol[db + (i0)]; \
  float v1 = RL(x2, i1) + Ccol[db + (i1)]; \
  float v2 = RL(x2, i2) + Ccol[db + (i2)]; \
  float v3 = RL(x2, i3) + Ccol[db + (i3)]; \
  float v4 = RL(x2, i4) + Ccol[db + (i4)]; \
  float v5 = RL(x2, i5) + Ccol[db + (i5)]; \
  float v6 = RL(x2, i6) + Ccol[db + (i6)]; \
  float v7 = RL(x2, i7) + Ccol[db + (i7)]; \
  bool p0 = v1 > v0; float a0 = p0 ? v1 : v0; int n0 = p0 ? (i1) : (i0); \
  bool p1 = v3 > v2; float a1 = p1 ? v3 : v2; int n1 = p1 ? (i3) : (i2); \
  bool p2 = v5 > v4; float a2 = p2 ? v5 : v4; int n2 = p2 ? (i5) : (i4); \
  bool p3 = v7 > v6; float a3 = p3 ? v7 : v6; int n3 = p3 ? (i7) : (i6); \
  bool r0 = a1 > a0; float bb0 = r0 ? a1 : a0; int m0 = r0 ? n1 : n0; \
  bool r1 = a3 > a2; float bb1 = r1 ? a3 : a2; int m1 = r1 ? n3 : n2; \
  bool s0 = bb1 > bb0; float gg = s0 ? bb1 : bb0; int w0 = s0 ? m1 : m0; \
  bool u0 = gg > bv; bv = u0 ? gg : bv; bi = u0 ? w0 : bi; }

// ============================ ASM text pieces ============================
// x broadcast: lane j writes x_j to xbuf[j]; 16 uniform-address b128 reads
// deliver x0..x63 (identical in all lanes) into v160-v223 as pairs.
#define XBCAST \
  "ds_write_b32 v15, %[x]\n\t" \
  "ds_read_b128 v[160:163], v10\n\t" \
  "ds_read_b128 v[164:167], v10 offset:16\n\t" \
  "ds_read_b128 v[168:171], v10 offset:32\n\t" \
  "ds_read_b128 v[172:175], v10 offset:48\n\t" \
  "ds_read_b128 v[176:179], v10 offset:64\n\t" \
  "ds_read_b128 v[180:183], v10 offset:80\n\t" \
  "ds_read_b128 v[184:187], v10 offset:96\n\t" \
  "ds_read_b128 v[188:191], v10 offset:112\n\t" \
  "ds_read_b128 v[192:195], v10 offset:128\n\t" \
  "ds_read_b128 v[196:199], v10 offset:144\n\t" \
  "ds_read_b128 v[200:203], v10 offset:160\n\t" \
  "ds_read_b128 v[204:207], v10 offset:176\n\t" \
  "ds_read_b128 v[208:211], v10 offset:192\n\t" \
  "ds_read_b128 v[212:215], v10 offset:208\n\t" \
  "ds_read_b128 v[216:219], v10 offset:224\n\t" \
  "ds_read_b128 v[220:223], v10 offset:240\n\t"

// Forward dot: 32 packed FMAs, 4 rotating acc pairs, counted waits.
#define NF_DOT \
  XBCAST \
  "s_waitcnt lgkmcnt(12)\n\t" \
  "v_pk_mul_f32 v[16:17], v[160:161], v[64:65]\n\t" \
  "v_pk_mul_f32 v[18:19], v[162:163], v[66:67]\n\t" \
  "v_pk_mul_f32 v[20:21], v[164:165], v[68:69]\n\t" \
  "v_pk_mul_f32 v[22:23], v[166:167], v[70:71]\n\t" \
  "v_pk_fma_f32 v[16:17], v[168:169], v[72:73], v[16:17]\n\t" \
  "v_pk_fma_f32 v[18:19], v[170:171], v[74:75], v[18:19]\n\t" \
  "v_pk_fma_f32 v[20:21], v[172:173], v[76:77], v[20:21]\n\t" \
  "v_pk_fma_f32 v[22:23], v[174:175], v[78:79], v[22:23]\n\t" \
  "s_waitcnt lgkmcnt(8)\n\t" \
  "v_pk_fma_f32 v[16:17], v[176:177], v[80:81], v[16:17]\n\t" \
  "v_pk_fma_f32 v[18:19], v[178:179], v[82:83], v[18:19]\n\t" \
  "v_pk_fma_f32 v[20:21], v[180:181], v[84:85], v[20:21]\n\t" \
  "v_pk_fma_f32 v[22:23], v[182:183], v[86:87], v[22:23]\n\t" \
  "v_pk_fma_f32 v[16:17], v[184:185], v[88:89], v[16:17]\n\t" \
  "v_pk_fma_f32 v[18:19], v[186:187], v[90:91], v[18:19]\n\t" \
  "v_pk_fma_f32 v[20:21], v[188:189], v[92:93], v[20:21]\n\t" \
  "v_pk_fma_f32 v[22:23], v[190:191], v[94:95], v[22:23]\n\t" \
  "s_waitcnt lgkmcnt(4)\n\t" \
  "v_pk_fma_f32 v[16:17], v[192:193], v[96:97], v[16:17]\n\t" \
  "v_pk_fma_f32 v[18:19], v[194:195], v[98:99], v[18:19]\n\t" \
  "v_pk_fma_f32 v[20:21], v[196:197], v[100:101], v[20:21]\n\t" \
  "v_pk_fma_f32 v[22:23], v[198:199], v[102:103], v[22:23]\n\t" \
  "v_pk_fma_f32 v[16:17], v[200:201], v[104:105], v[16:17]\n\t" \
  "v_pk_fma_f32 v[18:19], v[202:203], v[106:107], v[18:19]\n\t" \
  "v_pk_fma_f32 v[20:21], v[204:205], v[108:109], v[20:21]\n\t" \
  "v_pk_fma_f32 v[22:23], v[206:207], v[110:111], v[22:23]\n\t" \
  "s_waitcnt lgkmcnt(0)\n\t" \
  "v_pk_fma_f32 v[16:17], v[208:209], v[112:113], v[16:17]\n\t" \
  "v_pk_fma_f32 v[18:19], v[210:211], v[114:115], v[18:19]\n\t" \
  "v_pk_fma_f32 v[20:21], v[212:213], v[116:117], v[20:21]\n\t" \
  "v_pk_fma_f32 v[22:23], v[214:215], v[118:119], v[22:23]\n\t" \
  "v_pk_fma_f32 v[16:17], v[216:217], v[120:121], v[16:17]\n\t" \
  "v_pk_fma_f32 v[18:19], v[218:219], v[122:123], v[18:19]\n\t" \
  "v_pk_fma_f32 v[20:21], v[220:221], v[124:125], v[20:21]\n\t" \
  "v_pk_fma_f32 v[22:23], v[222:223], v[126:127], v[22:23]\n\t" \
  "v_add_f32 v16, v16, v18\n\t" \
  "v_add_f32 v20, v20, v22\n\t" \
  "v_add_f32 v17, v17, v19\n\t" \
  "v_add_f32 v21, v21, v23\n\t" \
  "v_add_f32 v16, v16, v20\n\t" \
  "v_add_f32 v17, v17, v21\n\t" \
  "v_add_f32 v16, v16, v17\n\t"

// Viterbi: 32 in-place packed adds + 32-op max3 tree (exact).
#define VM3(d,a,b,c) "v_max3_f32 v" #d ", v" #a ", v" #b ", v" #c "\n\t"
#define NV_DOT \
  XBCAST \
  "s_waitcnt lgkmcnt(12)\n\t" \
  "v_pk_add_f32 v[160:161], v[160:161], v[64:65]\n\t" \
  "v_pk_add_f32 v[162:163], v[162:163], v[66:67]\n\t" \
  "v_pk_add_f32 v[164:165], v[164:165], v[68:69]\n\t" \
  "v_pk_add_f32 v[166:167], v[166:167], v[70:71]\n\t" \
  "v_pk_add_f32 v[168:169], v[168:169], v[72:73]\n\t" \
  "v_pk_add_f32 v[170:171], v[170:171], v[74:75]\n\t" \
  "v_pk_add_f32 v[172:173], v[172:173], v[76:77]\n\t" \
  "v_pk_add_f32 v[174:175], v[174:175], v[78:79]\n\t" \
  "s_waitcnt lgkmcnt(8)\n\t" \
  "v_pk_add_f32 v[176:177], v[176:177], v[80:81]\n\t" \
  "v_pk_add_f32 v[178:179], v[178:179], v[82:83]\n\t" \
  "v_pk_add_f32 v[180:181], v[180:181], v[84:85]\n\t" \
  "v_pk_add_f32 v[182:183], v[182:183], v[86:87]\n\t" \
  "v_pk_add_f32 v[184:185], v[184:185], v[88:89]\n\t" \
  "v_pk_add_f32 v[186:187], v[186:187], v[90:91]\n\t" \
  "v_pk_add_f32 v[188:189], v[188:189], v[92:93]\n\t" \
  "v_pk_add_f32 v[190:191], v[190:191], v[94:95]\n\t" \
  "s_waitcnt lgkmcnt(4)\n\t" \
  "v_pk_add_f32 v[192:193], v[192:193], v[96:97]\n\t" \
  "v_pk_add_f32 v[194:195], v[194:195], v[98:99]\n\t" \
  "v_pk_add_f32 v[196:197], v[196:197], v[100:101]\n\t" \
  "v_pk_add_f32 v[198:199], v[198:199], v[102:103]\n\t" \
  "v_pk_add_f32 v[200:201], v[200:201], v[104:105]\n\t" \
  "v_pk_add_f32 v[202:203], v[202:203], v[106:107]\n\t" \
  "v_pk_add_f32 v[204:205], v[204:205], v[108:109]\n\t" \
  "v_pk_add_f32 v[206:207], v[206:207], v[110:111]\n\t" \
  "s_waitcnt lgkmcnt(0)\n\t" \
  "v_pk_add_f32 v[208:209], v[208:209], v[112:113]\n\t" \
  "v_pk_add_f32 v[210:211], v[210:211], v[114:115]\n\t" \
  "v_pk_add_f32 v[212:213], v[212:213], v[116:117]\n\t" \
  "v_pk_add_f32 v[214:215], v[214:215], v[118:119]\n\t" \
  "v_pk_add_f32 v[216:217], v[216:217], v[120:121]\n\t" \
  "v_pk_add_f32 v[218:219], v[218:219], v[122:123]\n\t" \
  "v_pk_add_f32 v[220:221], v[220:221], v[124:125]\n\t" \
  "v_pk_add_f32 v[222:223], v[222:223], v[126:127]\n\t" \
  VM3(160,160,161,162) VM3(163,163,164,165) VM3(166,166,167,168) \
  VM3(169,169,170,171) VM3(172,172,173,174) VM3(175,175,176,177) \
  VM3(178,178,179,180) VM3(181,181,182,183) VM3(184,184,185,186) \
  VM3(187,187,188,189) VM3(190,190,191,192) VM3(193,193,194,195) \
  VM3(196,196,197,198) VM3(199,199,200,201) VM3(202,202,203,204) \
  VM3(205,205,206,207) VM3(208,208,209,210) VM3(211,211,212,213) \
  VM3(214,214,215,216) VM3(217,217,218,219) VM3(220,220,221,222) \
  VM3(160,160,163,166) VM3(169,169,172,175) VM3(178,178,181,184) \
  VM3(187,187,190,193) VM3(196,196,199,202) VM3(205,205,208,211) \
  VM3(214,214,217,220) \
  VM3(160,160,169,178) VM3(187,187,196,205) \
  VM3(160,160,187,214) \
  "v_max_f32 v160, v160, v223\n\t"

#define AGLD(N,OFF) "global_load_dword v" #N ", v13, %[tp] offset:" #OFF "\n\t"
#define AGLE(N,OFF) "global_load_dword v" #N ", v12, %[ep] offset:" #OFF "\n\t"
#define AGLM(N,OFF) "global_load_dword v" #N ", v14, %[mp] offset:" #OFF "\n\t"

#define ELOADS \
  AGLD(64,0) AGLD(65,256) AGLD(66,512) AGLD(67,768) AGLD(68,1024) AGLD(69,1280) \
  AGLD(70,1536) AGLD(71,1792) AGLD(72,2048) AGLD(73,2304) AGLD(74,2560) AGLD(75,2816) \
  AGLD(76,3072) AGLD(77,3328) AGLD(78,3584) AGLD(79,3840) \
  "v_add_u32 v13, 0x1000, v13\n\t" \
  AGLD(80,0) AGLD(81,256) AGLD(82,512) AGLD(83,768) AGLD(84,1024) AGLD(85,1280) \
  AGLD(86,1536) AGLD(87,1792) AGLD(88,2048) AGLD(89,2304) AGLD(90,2560) AGLD(91,2816) \
  AGLD(92,3072) AGLD(93,3328) AGLD(94,3584) AGLD(95,3840) \
  "v_add_u32 v13, 0x1000, v13\n\t" \
  AGLD(96,0) AGLD(97,256) AGLD(98,512) AGLD(99,768) AGLD(100,1024) AGLD(101,1280) \
  AGLD(102,1536) AGLD(103,1792) AGLD(104,2048) AGLD(105,2304) AGLD(106,2560) AGLD(107,2816) \
  AGLD(108,3072) AGLD(109,3328) AGLD(110,3584) AGLD(111,3840) \
  "v_add_u32 v13, 0x1000, v13\n\t" \
  AGLD(112,0) AGLD(113,256) AGLD(114,512) AGLD(115,768) AGLD(116,1024) AGLD(117,1280) \
  AGLD(118,1536) AGLD(119,1792) AGLD(120,2048) AGLD(121,2304) AGLD(122,2560) AGLD(123,2816) \
  AGLD(124,3072) AGLD(125,3328) AGLD(126,3584) AGLD(127,3840)

#define AMUL(N) "v_mul_f32 v" #N ", 0x3fb8aa3b, v" #N "\n\t"
#define AEXI(N) "v_exp_f32 v" #N ", v" #N "\n\t"
#define EEXPALL \
  AMUL(64) AMUL(65) AMUL(66) AMUL(67) AMUL(68) AMUL(69) AMUL(70) AMUL(71) \
  AMUL(72) AMUL(73) AMUL(74) AMUL(75) AMUL(76) AMUL(77) AMUL(78) AMUL(79) \
  AMUL(80) AMUL(81) AMUL(82) AMUL(83) AMUL(84) AMUL(85) AMUL(86) AMUL(87) \
  AMUL(88) AMUL(89) AMUL(90) AMUL(91) AMUL(92) AMUL(93) AMUL(94) AMUL(95) \
  AMUL(96) AMUL(97) AMUL(98) AMUL(99) AMUL(100) AMUL(101) AMUL(102) AMUL(103) \
  AMUL(104) AMUL(105) AMUL(106) AMUL(107) AMUL(108) AMUL(109) AMUL(110) AMUL(111) \
  AMUL(112) AMUL(113) AMUL(114) AMUL(115) AMUL(116) AMUL(117) AMUL(118) AMUL(119) \
  AMUL(120) AMUL(121) AMUL(122) AMUL(123) AMUL(124) AMUL(125) AMUL(126) AMUL(127) \
  AEXI(64) AEXI(65) AEXI(66) AEXI(67) AEXI(68) AEXI(69) AEXI(70) AEXI(71) \
  AEXI(72) AEXI(73) AEXI(74) AEXI(75) AEXI(76) AEXI(77) AEXI(78) AEXI(79) \
  AEXI(80) AEXI(81) AEXI(82) AEXI(83) AEXI(84) AEXI(85) AEXI(86) AEXI(87) \
  AEXI(88) AEXI(89) AEXI(90) AEXI(91) AEXI(92) AEXI(93) AEXI(94) AEXI(95) \
  AEXI(96) AEXI(97) AEXI(98) AEXI(99) AEXI(100) AEXI(101) AEXI(102) AEXI(103) \
  AEXI(104) AEXI(105) AEXI(106) AEXI(107) AEXI(108) AEXI(109) AEXI(110) AEXI(111) \
  AEXI(112) AEXI(113) AEXI(114) AEXI(115) AEXI(116) AEXI(117) AEXI(118) AEXI(119) \
  AEXI(120) AEXI(121) AEXI(122) AEXI(123) AEXI(124) AEXI(125) AEXI(126) AEXI(127)

#define EMIS16 \
  AGLE(40,0) AGLE(41,256) AGLE(42,512) AGLE(43,768) AGLE(44,1024) AGLE(45,1280) \
  AGLE(46,1536) AGLE(47,1792) AGLE(48,2048) AGLE(49,2304) AGLE(50,2560) AGLE(51,2816) \
  AGLE(52,3072) AGLE(53,3328) AGLE(54,3584) AGLE(55,3840)
#define EMIS8 \
  AGLE(40,0) AGLE(41,256) AGLE(42,512) AGLE(43,768) AGLE(44,1024) AGLE(45,1280) \
  AGLE(46,1536) AGLE(47,1792)
#define EMIS16B \
  AGLE(24,0) AGLE(25,256) AGLE(26,512) AGLE(27,768) AGLE(28,1024) AGLE(29,1280) \
  AGLE(30,1536) AGLE(31,1792) AGLE(32,2048) AGLE(33,2304) AGLE(34,2560) AGLE(35,2816) \
  AGLE(36,3072) AGLE(37,3328) AGLE(38,3584) AGLE(39,3840)
#define EMIS8B \
  AGLE(24,0) AGLE(25,256) AGLE(26,512) AGLE(27,768) AGLE(28,1024) AGLE(29,1280) \
  AGLE(30,1536) AGLE(31,1792)
#define MASK16 \
  AGLM(128,0) AGLM(129,4) AGLM(130,8) AGLM(131,12) AGLM(132,16) AGLM(133,20) \
  AGLM(134,24) AGLM(135,28) AGLM(136,32) AGLM(137,36) AGLM(138,40) AGLM(139,44) \
  AGLM(140,48) AGLM(141,52) AGLM(142,56) AGLM(143,60)
#define MASK16B \
  AGLM(144,0) AGLM(145,4) AGLM(146,8) AGLM(147,12) AGLM(148,16) AGLM(149,20) \
  AGLM(150,24) AGLM(151,28) AGLM(152,32) AGLM(153,36) AGLM(154,40) AGLM(155,44) \
  AGLM(156,48) AGLM(157,52) AGLM(158,56) AGLM(159,60)
#define MASK8B \
  AGLM(144,0) AGLM(145,4) AGLM(146,8) AGLM(147,12) AGLM(148,16) AGLM(149,20) \
  AGLM(150,24) AGLM(151,28)

#define MOVMSK \
  "v_mov_b32 v128, v144\n\tv_mov_b32 v129, v145\n\tv_mov_b32 v130, v146\n\t" \
  "v_mov_b32 v131, v147\n\tv_mov_b32 v132, v148\n\tv_mov_b32 v133, v149\n\t" \
  "v_mov_b32 v134, v150\n\tv_mov_b32 v135, v151\n\tv_mov_b32 v136, v152\n\t" \
  "v_mov_b32 v137, v153\n\tv_mov_b32 v138, v154\n\tv_mov_b32 v139, v155\n\t" \
  "v_mov_b32 v140, v156\n\tv_mov_b32 v141, v157\n\tv_mov_b32 v142, v158\n\t" \
  "v_mov_b32 v143, v159\n\t"
#define MOVEMI \
  "v_mov_b32 v40, v24\n\tv_mov_b32 v41, v25\n\tv_mov_b32 v42, v26\n\t" \
  "v_mov_b32 v43, v27\n\tv_mov_b32 v44, v28\n\tv_mov_b32 v45, v29\n\t" \
  "v_mov_b32 v46, v30\n\tv_mov_b32 v47, v31\n\tv_mov_b32 v48, v32\n\t" \
  "v_mov_b32 v49, v33\n\tv_mov_b32 v50, v34\n\tv_mov_b32 v51, v35\n\t" \
  "v_mov_b32 v52, v36\n\tv_mov_b32 v53, v37\n\tv_mov_b32 v54, v38\n\t" \
  "v_mov_b32 v55, v39\n\t"

#define AEM(D,R) "v_mul_f32 v" #D ", 0x3fb8aa3b, v" #R "\n\t"
#define EMEXP16 \
  AEM(24,40) AEM(25,41) AEM(26,42) AEM(27,43) AEM(28,44) AEM(29,45) AEM(30,46) AEM(31,47) \
  AEM(32,48) AEM(33,49) AEM(34,50) AEM(35,51) AEM(36,52) AEM(37,53) AEM(38,54) AEM(39,55) \
  AEXI(24) AEXI(25) AEXI(26) AEXI(27) AEXI(28) AEXI(29) AEXI(30) AEXI(31) \
  AEXI(32) AEXI(33) AEXI(34) AEXI(35) AEXI(36) AEXI(37) AEXI(38) AEXI(39)
#define EMEXP8 \
  AEM(24,40) AEM(25,41) AEM(26,42) AEM(27,43) AEM(28,44) AEM(29,45) AEM(30,46) AEM(31,47) \
  AEXI(24) AEXI(25) AEXI(26) AEXI(27) AEXI(28) AEXI(29) AEXI(30) AEXI(31)

#define NFSTEP(MR,EV) \
  "v_cmp_ne_u32 vcc, 0, v" #MR "\n\t" \
  NF_DOT \
  "v_mul_f32 v16, v16, v" #EV "\n\t" \
  "v_cndmask_b32 %[x], %[x], v16, vcc\n\t"

#define RNRM \
  "v_mov_b32 v17, %[x]\n\t" \
  "ds_swizzle_b32 v18, v17 offset:0x041F\n\t" \
  "s_waitcnt lgkmcnt(0)\n\t" \
  "v_max_f32 v17, v17, v18\n\t" \
  "ds_swizzle_b32 v18, v17 offset:0x081F\n\t" \
  "s_waitcnt lgkmcnt(0)\n\t" \
  "v_max_f32 v17, v17, v18\n\t" \
  "ds_swizzle_b32 v18, v17 offset:0x101F\n\t" \
  "s_waitcnt lgkmcnt(0)\n\t" \
  "v_max_f32 v17, v17, v18\n\t" \
  "ds_swizzle_b32 v18, v17 offset:0x201F\n\t" \
  "s_waitcnt lgkmcnt(0)\n\t" \
  "v_max_f32 v17, v17, v18\n\t" \
  "ds_swizzle_b32 v18, v17 offset:0x401F\n\t" \
  "s_waitcnt lgkmcnt(0)\n\t" \
  "v_max_f32 v17, v17, v18\n\t" \
  "v_readlane_b32 s56, v17, 0\n\t" \
  "v_readlane_b32 s57, v17, 32\n\t" \
  "v_mov_b32 v18, s57\n\t" \
  "v_max_f32 v18, s56, v18\n\t" \
  "v_readlane_b32 s56, v18, 0\n\t"

#define NFSTEPR(MR,EV) \
  "v_cmp_ne_u32 vcc, 0, v" #MR "\n\t" \
  NF_DOT \
  "v_mul_f32 v16, v16, v" #EV "\n\t" \
  RNRM \
  "v_cndmask_b32 %[x], %[x], v16, vcc\n\t" \
  "v_rcp_f32 v18, s56\n\t" \
  "v_log_f32 v19, s56\n\t" \
  "v_mul_f32 %[x], %[x], v18\n\t" \
  "v_fmac_f32 %[off], 0x3f317218, v19\n\t"

#define NVSTEP(MR,EV) \
  "v_cmp_ne_u32 vcc, 0, v" #MR "\n\t" \
  NV_DOT \
  "v_add_f32 v16, v160, v" #EV "\n\t" \
  "v_cndmask_b32 %[x], %[x], v16, vcc\n\t"

#define FSTEPS16 \
  NFSTEPR(128,24) NFSTEP(129,25) NFSTEP(130,26) NFSTEP(131,27) \
  NFSTEP(132,28)  NFSTEP(133,29) NFSTEP(134,30) NFSTEP(135,31) \
  NFSTEPR(136,32) NFSTEP(137,33) NFSTEP(138,34) NFSTEP(139,35) \
  NFSTEP(140,36)  NFSTEP(141,37) NFSTEP(142,38) NFSTEP(143,39)
#define VSTEPS16 \
  NVSTEP(128,40) NVSTEP(129,41) NVSTEP(130,42) NVSTEP(131,43) \
  NVSTEP(132,44) NVSTEP(133,45) NVSTEP(134,46) NVSTEP(135,47) \
  NVSTEP(136,48) NVSTEP(137,49) NVSTEP(138,50) NVSTEP(139,51) \
  NVSTEP(140,52) NVSTEP(141,53) NVSTEP(142,54) NVSTEP(143,55)

#define CLOBS \
  "v10","v11","v12","v13","v14","v15","v16","v17","v18","v19","v20","v21", \
  "v22","v23","v24","v25","v26","v27","v28","v29","v30","v31","v32","v33", \
  "v34","v35","v36","v37","v38","v39","v40","v41","v42","v43","v44","v45", \
  "v46","v47","v48","v49","v50","v51","v52","v53","v54","v55", \
  "v64","v65","v66","v67","v68","v69","v70","v71","v72","v73","v74","v75", \
  "v76","v77","v78","v79","v80","v81","v82","v83","v84","v85","v86","v87", \
  "v88","v89","v90","v91","v92","v93","v94","v95","v96","v97","v98","v99", \
  "v100","v101","v102","v103","v104","v105","v106","v107","v108","v109", \
  "v110","v111","v112","v113","v114","v115","v116","v117","v118","v119", \
  "v120","v121","v122","v123","v124","v125","v126","v127","v128","v129", \
  "v130","v131","v132","v133","v134","v135","v136","v137","v138","v139", \
  "v140","v141","v142","v143","v144","v145","v146","v147","v148","v149", \
  "v150","v151","v152","v153","v154","v155","v156","v157","v158","v159", \
  "v160","v161","v162","v163","v164","v165","v166","v167","v168","v169", \
  "v170","v171","v172","v173","v174","v175","v176","v177","v178","v179", \
  "v180","v181","v182","v183","v184","v185","v186","v187","v188","v189", \
  "v190","v191","v192","v193","v194","v195","v196","v197","v198","v199", \
  "v200","v201","v202","v203","v204","v205","v206","v207","v208","v209", \
  "v210","v211","v212","v213","v214","v215","v216","v217","v218","v219", \
  "v220","v221","v222","v223", \
  "s55","s56","s57","vcc","scc","memory"

__global__ __launch_bounds__(512)
__attribute__((amdgpu_waves_per_eu(1, 2)))
void crf_mega_kernel(
    const float* __restrict__ em, const int* __restrict__ mask,
    const float* __restrict__ trans, const int* __restrict__ tags,
    float* __restrict__ out_dec, float* ll_sum, int* match, int* maskSum) {

  __shared__ float Ecol[KK * CS];               // exp(T) columns (C++ head/t1)
  __shared__ float Ccol[KK * CS];               // raw T columns (tail + phase B)
  __shared__ __align__(16) float xbfF[KK];      // fwd x broadcast buffer
  __shared__ __align__(16) float xbfV[KK];      // vit x broadcast buffer
  __shared__ __align__(16) float ckw[64][KK];   // vit deltas every 16 steps
  __shared__ float fin[KK];                     // final vit delta (t=1023)
  __shared__ unsigned char mrow[TT];
  __shared__ unsigned char bpl[TT][KK];
  __shared__ unsigned char segm[32][KK];
  __shared__ unsigned char bs[40];
  __shared__ int redm[32];

  const int b = blockIdx.x;
  const int tid = threadIdx.x;
  const int wv = tid >> 6;
  const int j = tid & 63;
  const int jb65 = j * CS;

  const float* emb = em + (size_t)b * TT * KK;
  const int* mb = mask + (size_t)b * TT;
  const int* tgb = tags + (size_t)b * TT;

  for (int t = tid; t < TT; t += 512) mrow[t] = (unsigned char)(mb[t] ? 1 : 0);
  if (wv == 0) {
#pragma unroll 4
    for (int i = 0; i < KK; ++i) Ecol[jb65 + i] = __expf(trans[i * KK + j]);
  } else if (wv == 1) {
#pragma unroll 4
    for (int i = 0; i < KK; ++i) Ccol[jb65 + i] = trans[i * KK + j];
  }
  __syncthreads();  // B0

  if (wv == 0) {
    // =========================== FORWARD (wave 0) ===========================
    float raw = emb[j];
    float x, offset;
    {  // t = 1 special
      float m0 = wavemax(raw);
      offset = m0;
      float s = __expf(raw - m0);
      int eb = jb65; asm volatile("" : "+v"(eb));
      float q0 = 0.f, q1 = 0.f, q2 = 0.f, q3 = 0.f;
      CFQALL(s)
      float q = (q0 + q1) + (q2 + q3);
      q *= __expf(emb[KK + j]);
      x = mrow[1] ? q : s;
    }
    // head t = 2..7 (no renorm in range)
    for (int t = 2; t <= 7; ++t) {
      float e = __expf(emb[(size_t)t * KK + j]);
      int m = mrow[t];
      CFWD_STEP(t, e, m)
    }
    unsigned xr = (unsigned)(unsigned long long)(&xbfF[0]);
    unsigned xw = xr + 4u * (unsigned)j;
    // asm chain t = 8..1023: 62-iter loop + peeled iter62 + 8-step tail.
    asm volatile(
      "s_mov_b32 s55, 0\n\t"
      "v_mov_b32 v10, %[xr]\n\t"
      "v_mov_b32 v15, %[xw]\n\t"
      "v_mov_b32 v12, %[vo]\n\t"
      "v_mov_b32 v13, %[jo]\n\t"
      "v_mov_b32 v14, 32\n\t"
      "s_waitcnt lgkmcnt(0)\n\t"
      ELOADS
      MASK16
      EMIS16
      "s_waitcnt vmcnt(0)\n\t"
      EEXPALL
      "9:\n\t"
      EMEXP16
      "v_add_u32 v12, 0x1000, v12\n\t"
      EMIS16
      "v_add_u32 v14, 64, v14\n\t"
      MASK16B
      FSTEPS16
      "s_waitcnt vmcnt(0)\n\t"
      MOVMSK
      "s_add_u32 s55, s55, 1\n\t"
      "s_cmp_lt_u32 s55, 62\n\t"
      "s_cbranch_scc1 9b\n\t"
      // peeled iter 62 (t=1000..1015): prefetch 8-step tail into B regs
      EMEXP16
      "v_add_u32 v12, 0x1000, v12\n\t"
      EMIS8
      "v_add_u32 v14, 64, v14\n\t"
      MASK8B
      FSTEPS16
      "s_waitcnt vmcnt(0)\n\t"
      // tail t = 1016..1023 (renorm at 1016 only)
      EMEXP8
      NFSTEPR(144,24) NFSTEP(145,25) NFSTEP(146,26) NFSTEP(147,27)
      NFSTEP(148,28)  NFSTEP(149,29) NFSTEP(150,30) NFSTEP(151,31)
      "s_waitcnt vmcnt(0) lgkmcnt(0)\n\t"
      : [x]"+v"(x), [off]"+v"(offset)
      : [ep]"s"(emb), [mp]"s"(mb), [tp]"s"(trans),
        [vo]"v"(2048 + 4 * j), [jo]"v"(4 * j), [xr]"v"(xr), [xw]"v"(xw)
      : CLOBS);

    float ssum = x;
#pragma unroll
    for (int off = 1; off <= 32; off <<= 1) ssum += __shfl_xor(ssum, off);
    if (tid == 0) atomicAdd(ll_sum, -(offset + __logf(ssum)));

  } else if (wv == 1) {
    // ====================== VITERBI max-only (wave 1) ======================
    float x = emb[j];
    unsigned ckoff = (unsigned)(unsigned long long)(&ckw[1][j]);
    unsigned xr = (unsigned)(unsigned long long)(&xbfV[0]);
    unsigned xw = xr + 4u * (unsigned)j;
    asm volatile(
      "s_mov_b32 s55, 0\n\t"
      "v_mov_b32 v10, %[xr]\n\t"
      "v_mov_b32 v15, %[xw]\n\t"
      "v_mov_b32 v11, %[ck]\n\t"
      "v_mov_b32 v12, %[vo]\n\t"
      "v_mov_b32 v13, %[jo]\n\t"
      "v_mov_b32 v14, 4\n\t"
      "s_waitcnt lgkmcnt(0)\n\t"
      ELOADS
      MASK16
      EMIS16
      "s_waitcnt vmcnt(0)\n\t"
      "8:\n\t"
      "v_add_u32 v12, 0x1000, v12\n\t"
      EMIS16B
      "v_add_u32 v14, 64, v14\n\t"
      MASK16B
      VSTEPS16
      "ds_write_b32 v11, %[x]\n\t"
      "v_add_u32 v11, 0x100, v11\n\t"
      "s_waitcnt vmcnt(0)\n\t"
      MOVEMI
      MOVMSK
      "s_add_u32 s55, s55, 1\n\t"
      "s_cmp_lt_u32 s55, 62\n\t"
      "s_cbranch_scc1 8b\n\t"
      // peeled iter 62 (t=993..1008): prefetch 8-step tail into B regs
      "v_add_u32 v12, 0x1000, v12\n\t"
      EMIS8B
      "v_add_u32 v14, 64, v14\n\t"
      MASK8B
      VSTEPS16
      "ds_write_b32 v11, %[x]\n\t"
      "s_waitcnt vmcnt(0)\n\t"
      // tail t = 1009..1016
      NVSTEP(144,24) NVSTEP(145,25) NVSTEP(146,26) NVSTEP(147,27)
      NVSTEP(148,28) NVSTEP(149,29) NVSTEP(150,30) NVSTEP(151,31)
      "s_waitcnt vmcnt(0) lgkmcnt(0)\n\t"
      : [x]"+v"(x)
      : [ep]"s"(emb), [mp]"s"(mb), [tp]"s"(trans),
        [vo]"v"(256 + 4 * j), [jo]"v"(4 * j), [ck]"v"(ckoff),
        [xr]"v"(xr), [xw]"v"(xw)
      : CLOBS);
    // C++ tail t = 1017..1023 (7 steps)
    for (int t = TT - 7; t <= TT - 1; ++t) {
      float e = emb[(size_t)t * KK + j];
      int m = mrow[t];
      CVIT_STEP(t, e, m)
    }
    fin[j] = x;

  } else if (wv == 2) {
    // ========================= PATH SCORE (wave 2) =========================
    float acc = 0.f;
    int cnt = 0;
    for (int t = j; t < TT; t += 64) {
      if (mb[t]) {
        int tg = tgb[t];
        acc += emb[(size_t)t * KK + tg];
        cnt += 1;
        if (t >= 1) acc += trans[tgb[t - 1] * KK + tg];
      }
    }
#pragma unroll
    for (int off = 1; off <= 32; off <<= 1) {
      acc += __shfl_xor(acc, off);
      cnt += __shfl_xor(cnt, off);
    }
    if (j == 0) { atomicAdd(ll_sum, acc); atomicAdd(maskSum, cnt); }
  }
  // waves 3-7 fall through.

  __syncthreads();  // B1 — phase boundary (orders ckw, fin, Ccol)

  // ====== PHASE B: per-segment argmax recompute (8 waves x 4 segments) ======
#pragma unroll 1
  for (int kk = 0; kk < 4; ++kk) {
    int s = wv + 8 * kk;
    int tS = 32 * s + 1;
    int tE = (s == 31) ? (TT - 1) : (32 * s + 32);
    float x2 = (s == 0) ? emb[j] : ckw[2 * s][j];
    float e_nx = emb[(size_t)tS * KK + j];
#pragma unroll 1
    for (int t = tS; t <= tE; ++t) {
      float e = e_nx;
      if (t < tE) e_nx = emb[(size_t)(t + 1) * KK + j];
      int db = jb65; asm volatile("" : "+v"(db));
      float bv = -__builtin_inff(); int bi = 0;
      AG(0, 1, 2, 3, 4, 5, 6, 7)        AG(8, 9, 10, 11, 12, 13, 14, 15)
      AG(16, 17, 18, 19, 20, 21, 22, 23) AG(24, 25, 26, 27, 28, 29, 30, 31)
      AG(32, 33, 34, 35, 36, 37, 38, 39) AG(40, 41, 42, 43, 44, 45, 46, 47)
      AG(48, 49, 50, 51, 52, 53, 54, 55) AG(56, 57, 58, 59, 60, 61, 62, 63)
      int m = mrow[t];
      float nd = m ? (bv + e) : x2;
      int bp = m ? bi : j;
      bpl[t][j] = (unsigned char)bp;
      x2 = nd;
    }
  }
  __syncthreads();  // B2

  // ---- compose 32-step segment maps (4 chains per thread, ILP) ----
  {
    int j0 = tid & 63;
    int sg = tid >> 6;
    int xs[4]; int tS[4], tE[4];
#pragma unroll
    for (int kk = 0; kk < 4; ++kk) {
      int s = sg + 8 * kk;
      xs[kk] = j0;
      tS[kk] = 32 * s + 1;
      tE[kk] = (s == 31) ? (TT - 1) : (32 * s + 32);
    }
    for (int q = 0; q < 32; ++q) {
#pragma unroll
      for (int kk = 0; kk < 4; ++kk) {
        int t = tE[kk] - q;
        if (t >= tS[kk]) xs[kk] = bpl[t][xs[kk]];
      }
    }
#pragma unroll
    for (int kk = 0; kk < 4; ++kk) segm[sg + 8 * kk][j0] = (unsigned char)xs[kk];
  }
  __syncthreads();  // B3

  if (tid == 0) {   // last-tag argmax (strict >, first max) + boundary walk
    float bd = fin[0];
    int lt = 0;
    for (int i = 1; i < KK; ++i) {
      float v2 = fin[i];
      if (v2 > bd) { bd = v2; lt = i; }
    }
    bs[32] = (unsigned char)lt;
    for (int s = 31; s >= 0; --s) bs[s] = segm[s][bs[s + 1]];
  }
  __syncthreads();  // B4

  if (tid < 32) {   // per-segment backtrace
    int s = tid;
    int x = bs[s + 1];
    int cnt = 0;
    int tEnd = (s == 31) ? (TT - 1) : (32 * s + 32);
    if (s == 31) {
      int m = mrow[TT - 1];
      out_dec[(size_t)b * TT + TT - 1] = (float)(m ? x : 0);
      cnt += (m && x == tgb[TT - 1]);
    }
    for (int t = tEnd; t >= 32 * s + 1; --t) {
      x = bpl[t][x];
      int m2 = mrow[t - 1];
      out_dec[(size_t)b * TT + t - 1] = (float)(m2 ? x : 0);
      cnt += (m2 && x == tgb[t - 1]);
    }
    redm[s] = cnt;
  }
  __syncthreads();  // B5
  if (tid == 0) {
    int c = 0;
    for (int s = 0; s < 32; ++s) c += redm[s];
    atomicAdd(match, c);
  }
}

__global__ void finalize_kernel(const float* ll_sum, const int* match,
                                const int* maskSum, float* d_out) {
  d_out[0] = -(*ll_sum) / (float)BB;
  d_out[1 + BB * TT] = (float)(*match) / (float)(*maskSum);
}

extern "C" void kernel_launch(void* const* d_in, const int* in_sizes, int n_in,
                              void* d_out, int out_size, void* d_ws, size_t ws_size,
                              hipStream_t stream) {
  const float* em = (const float*)d_in[0];
  const int* tags = (const int*)d_in[1];
  const int* mask = (const int*)d_in[2];       // bool -> int32 on device
  const float* trans = (const float*)d_in[3];
  float* out = (float*)d_out;

  float* ll_sum = (float*)d_ws;
  int* match = (int*)((char*)d_ws + 4);
  int* maskSum = (int*)((char*)d_ws + 8);

  hipMemsetAsync(d_ws, 0, 12, stream);
  crf_mega_kernel<<<BB, 512, 0, stream>>>(em, mask, trans, tags, out + 1,
                                          ll_sum, match, maskSum);
  finalize_kernel<<<1, 1, 0, stream>>>(ll_sum, match, maskSum, out);
}